// Round 16
// baseline (2262.361 us; speedup 1.0000x reference)
//
#include <hip/hip_runtime.h>
#include <hip/hip_bf16.h>
#include <hip/hip_fp16.h>

#define VV 32000
#define EE 256
#define HH 512
#define BB 64
#define TT 64
#define SS 64
#define G3 1536   // 3*H
#define NGRU 256
#define STU 16384 // one packed state buffer: 256 kp x 64 b uints, layout (kp>>1)*128 + 2b + (kp&1)

typedef __attribute__((ext_vector_type(8))) short bf16x8;
typedef __attribute__((ext_vector_type(4))) float f32x4;
typedef _Float16 half2v __attribute__((ext_vector_type(2)));

__device__ __forceinline__ half2v bch(unsigned u) { return __builtin_bit_cast(half2v, u); }

__device__ __forceinline__ void async16(void* lds, const void* g) {
  __builtin_amdgcn_global_load_lds((const __attribute__((address_space(1))) void*)g,
                                   (__attribute__((address_space(3))) void*)lds, 16, 0, 0);
}

__device__ __forceinline__ float sigmoid_fast(float x) {
  return 1.0f / (1.0f + __expf(-x));
}
__device__ __forceinline__ float tanh_fast(float x) {
  x = fminf(fmaxf(x, -15.f), 15.f);
  float e = __expf(2.f * x);
  return (e - 1.f) / (e + 1.f);
}
__device__ __forceinline__ float2 unpackh2(unsigned u) {
  __half2 h = *reinterpret_cast<__half2*>(&u);
  return __half22float2(h);
}
__device__ __forceinline__ unsigned packh2(float x, float y) {
  __half2 h = __floats2half2_rn(x, y);
  return *reinterpret_cast<unsigned*>(&h);
}
__device__ __forceinline__ unsigned packh2w(float x, float y) {  // weight pack
  half2v h; h[0] = (_Float16)x; h[1] = (_Float16)y;
  return __builtin_bit_cast(unsigned, h);
}

// coherent stores: write-through past L2 to the IF coherence point (no fence needed)
__device__ __forceinline__ void stg_scu(unsigned* p, unsigned v) {
  asm volatile("global_store_dword %0, %1, off sc0 sc1" :: "v"(p), "v"(v) : "memory");
}
__device__ __forceinline__ void stg_scu2(unsigned* p, uint2 v) {
  asm volatile("global_store_dwordx2 %0, %1, off sc0 sc1" :: "v"(p), "v"(v) : "memory");
}
__device__ __forceinline__ void stg_sci(int* p, int v) {
  asm volatile("global_store_dword %0, %1, off sc0 sc1" :: "v"(p), "v"(v) : "memory");
}
__device__ __forceinline__ int ld_agent(const int* p) {
  return __hip_atomic_load(p, __ATOMIC_RELAXED, __HIP_MEMORY_SCOPE_AGENT);
}

// fence-free grid barrier, flag/master/broadcast form (r13-proven: ~3.5us).
// Arrival: one sc store per block (no RMW contention); master (block NBK-1)
// polls all flags with 64 lanes; all other blocks poll only the `go` line.
template <int NBK>
__device__ __forceinline__ void gbar(int* flags, int* go, int phase) {
  __syncthreads();   // drains vmcnt per wave -> this block's sc stores are at IF
  if (blockIdx.x == NBK - 1) {
    if (threadIdx.x < 64) {
      const int l = threadIdx.x;
      if (l == 0) stg_sci(&flags[NBK - 1], phase);
      for (;;) {
        bool ok = true;
#pragma unroll
        for (int g = 0; g < NBK / 64; ++g) ok &= (ld_agent(&flags[l + 64 * g]) >= phase);
        if (__all(ok)) break;
        __builtin_amdgcn_s_sleep(1);
      }
      if (l == 0) stg_sci(go, phase);
    }
  } else {
    if (threadIdx.x == 0) {
      stg_sci(&flags[blockIdx.x], phase);
      while (ld_agent(go) < phase) __builtin_amdgcn_s_sleep(1);
    }
  }
  __syncthreads();
}

// ---------------- strided 2D transpose: dst[c][r] = src[r*ld + off + c]
__global__ __launch_bounds__(256) void transpose_kernel(float* __restrict__ dst,
                                                        const float* __restrict__ src,
                                                        int R, int C, int ld, int off) {
  __shared__ float tile[32][33];
  int c0 = blockIdx.x * 32, r0 = blockIdx.y * 32;
  int x = threadIdx.x, y = threadIdx.y;     // block (32,8)
  for (int i = y; i < 32; i += 8) tile[i][x] = src[(size_t)(r0 + i) * ld + off + c0 + x];
  __syncthreads();
  for (int i = y; i < 32; i += 8) dst[(size_t)(c0 + i) * R + r0 + x] = tile[x][i];
}

// ---------------- fp32 -> bf16 cast
__global__ __launch_bounds__(256) void cast_kernel(const float* __restrict__ src,
                                                   __hip_bfloat16* __restrict__ dst, int n) {
  for (int i = blockIdx.x * blockDim.x + threadIdx.x; i < n; i += gridDim.x * blockDim.x)
    dst[i] = __float2bfloat16(src[i]);
}

// ---------------- fp32 pairs -> packed fp16 (half2) words
__global__ __launch_bounds__(256) void packhalf_kernel(const float* __restrict__ src,
                                                       unsigned* __restrict__ dst, int npairs) {
  for (int i = blockIdx.x * blockDim.x + threadIdx.x; i < npairs; i += gridDim.x * blockDim.x)
    dst[i] = packh2(src[2 * i], src[2 * i + 1]);
}

// ---------------- Wq[j][k] fp32 -> WqhT[kp][j] packed fp16 (k-pair transposed)
__global__ __launch_bounds__(256) void packWqT_kernel(const float* __restrict__ Wq,
                                                      unsigned* __restrict__ WqhT) {
  __shared__ unsigned tile[32][33];
  int kp0 = blockIdx.x * 32, j0 = blockIdx.y * 32;
  int x = threadIdx.x, y = threadIdx.y;   // block (32,8)
  for (int i = y; i < 32; i += 8) {
    int j = j0 + i, kp = kp0 + x;
    tile[i][x] = packh2(Wq[(size_t)j * HH + 2 * kp], Wq[(size_t)j * HH + 2 * kp + 1]);
  }
  __syncthreads();
  for (int i = y; i < 32; i += 8)
    WqhT[(size_t)(kp0 + i) * HH + j0 + x] = tile[x][i];
}

// ---------------- pack initial hidden state into (kp>>1)*128+2b+(kp&1) fp16-pair layout
__global__ __launch_bounds__(256) void hspack_kernel(const float* __restrict__ hs,
                                                     unsigned* __restrict__ h0u,
                                                     unsigned* __restrict__ h1u) {
  int i = blockIdx.x * 256 + threadIdx.x;   // 0..32767
  int layer = i >> 14, r = i & 16383;
  int b = r >> 8, kp = r & 255;
  const float* src = hs + (size_t)layer * BB * HH + (size_t)b * HH + 2 * kp;
  unsigned u = packh2(src[0], src[1]);
  (layer ? h1u : h0u)[(kp >> 1) * 128 + 2 * b + (kp & 1)] = u;
}

// ---------------- tiled fp32 GEMM: C = A(row-gathered) * Bk (+bias)
// tbmaj==0: C[m][n];  tbmaj==1: C[(m>>6)][n][m&63]
__global__ __launch_bounds__(256) void gemm32_kernel(const float* __restrict__ A,
                                                     const int* __restrict__ Xtb,
                                                     const float* __restrict__ Bk,
                                                     const float* __restrict__ bias,
                                                     float* __restrict__ C,
                                                     int N, int K, int ldb, int tbmaj) {
  __shared__ float Xs[32][65];    // [k][m]
  __shared__ float Ws[32][129];   // [k][n]
  __shared__ int toks[64];
  int m0 = blockIdx.x * 64, n0 = blockIdx.y * 128;
  int tid = threadIdx.x;
  if (tid < 64) {
    int m = m0 + tid;
    toks[tid] = Xtb ? Xtb[(m & 63) * TT + (m >> 6)] : m;
  }
  __syncthreads();
  float acc[4][8];
#pragma unroll
  for (int i = 0; i < 4; ++i)
#pragma unroll
    for (int j = 0; j < 8; ++j) acc[i][j] = 0.f;
  int mi = (tid >> 4) * 4;   // 4 m per thread
  int ni = (tid & 15) * 8;   // 8 n per thread
  for (int kc = 0; kc < K; kc += 32) {
#pragma unroll
    for (int i = 0; i < 16; ++i) {
      int idx = tid + i * 256;          // 0..4095
      int kk = idx >> 7, nn = idx & 127;
      Ws[kk][nn] = Bk[(size_t)(kc + kk) * ldb + n0 + nn];
    }
#pragma unroll
    for (int i = 0; i < 8; ++i) {
      int idx = tid + i * 256;          // 0..2047
      int mm = idx >> 5, kk = idx & 31;
      Xs[kk][mm] = A[(size_t)toks[mm] * K + kc + kk];
    }
    __syncthreads();
#pragma unroll
    for (int k = 0; k < 32; ++k) {
      float xv[4], wv[8];
#pragma unroll
      for (int i = 0; i < 4; ++i) xv[i] = Xs[k][mi + i];
#pragma unroll
      for (int j = 0; j < 8; ++j) wv[j] = Ws[k][ni + j];
#pragma unroll
      for (int i = 0; i < 4; ++i)
#pragma unroll
        for (int j = 0; j < 8; ++j) acc[i][j] += xv[i] * wv[j];
    }
    __syncthreads();
  }
#pragma unroll
  for (int i = 0; i < 4; ++i) {
    int m = m0 + mi + i;
#pragma unroll
    for (int j = 0; j < 8; ++j) {
      int n = n0 + ni + j;
      float v = acc[i][j] + (bias ? bias[n] : 0.f);
      if (tbmaj) C[((size_t)(m >> 6) * N + n) * BB + (m & 63)] = v;
      else       C[(size_t)m * N + n] = v;
    }
  }
}

// ---------------- persistent recurrent kernel ----------------
// 3 phases / 3 barriers per step:
//  P1: attn blocks: self-q (WqhT coalesced fdot2) + scores + softmax + ctx.
//      HOIST GRU blocks: Wh0*h0p (waves 0-3) and Wh1*h1p (waves 4-7) -> LDS.
//  P2: GRU blocks: Wi0*ctx + combine -> h0n.
//  P3: GRU blocks: Wi1*h0n + combine -> h1n + bf16 outs.
struct RecArgs {
  const float *W_ih0, *W_hh0, *W_ih1, *W_hh1;
  const float *b_hh0, *b_ih1, *b_hh1;
  const float *gixT, *wv;           // gixT: [t][j(1536)][b] fp32
  const unsigned *WqhT;             // [kp][j] packed fp16
  const unsigned *keysph, *ench;    // fp16-packed [b*S+s][h/2]
  const int* vlen;
  const unsigned *h0i, *h1i;        // packed init state
  unsigned *ctxS, *h0S, *h1S;       // [TT][STU] one-shot
  int *flags, *go;
  __hip_bfloat16* outsb;
};

// fdot2 accumulation over nkp k-pairs (x packed fp16 state, W fp16 LDS).
__device__ __forceinline__ void accum6(const unsigned* __restrict__ xu, int xkp0,
                                       const unsigned (*__restrict__ WL)[8], int wkp0,
                                       int nkp, int b, float s[6]) {
#pragma unroll 4
  for (int i = 0; i < nkp; i += 2) {
    uint2 xv = *(const uint2*)(xu + ((xkp0 + i) >> 1) * 128 + 2 * b);
    half2v x0 = bch(xv.x), x1 = bch(xv.y);
    const unsigned* w0 = WL[wkp0 + i];
    const unsigned* w1 = WL[wkp0 + i + 1];
#pragma unroll
    for (int g = 0; g < 6; ++g) {
      s[g] = __builtin_amdgcn_fdot2(bch(w0[g]), x0, s[g], false);
      s[g] = __builtin_amdgcn_fdot2(bch(w1[g]), x1, s[g], false);
    }
  }
}

template <bool HOIST, int NBK>
__global__ __launch_bounds__(512, 4) void recurrent_kernel(RecArgs a) {
  const int blk = blockIdx.x, tid = threadIdx.x;
  const int w = tid >> 6, lane = tid & 63;
  const bool isGru = HOIST ? (blk < NGRU) : true;
  const bool isAttn = HOIST ? (blk >= NGRU) : (blk < BB);
  const int battn = HOIST ? (blk - NGRU) : blk;
  const int j0 = 2 * blk;   // valid for GRU blocks

  __shared__ __align__(16) unsigned WLh[2][512][8];  // [layer][kp][slot r0,r1,z0,z1,n0,n1,pad,pad]
  __shared__ float redW[6][8][64];
  __shared__ float redH0s[6][64], redH1s[6][64];
  __shared__ unsigned sH2[256];
  __shared__ float sQ[HH], sWV[HH], sCt[HH], sAttn[SS];

  // one-time fp16 weight preload
  if (isGru) {
    for (int idx = tid; idx < 2 * 3072; idx += 512) {
      int layer = idx / 3072;
      int rem = idx - layer * 3072;
      int kp = rem / 6, g = rem - kp * 6;
      int gate = g >> 1, jj = g & 1;
      int row = gate * 512 + j0 + jj;
      float w0, w1;
      if (layer == 0) {
        if (kp < 256) { w0 = a.W_ih0[(size_t)row * 768 + 2 * kp];
                        w1 = a.W_ih0[(size_t)row * 768 + 2 * kp + 1]; }
        else          { w0 = a.W_hh0[(size_t)row * 512 + 2 * (kp - 256)];
                        w1 = a.W_hh0[(size_t)row * 512 + 2 * (kp - 256) + 1]; }
      } else {
        if (kp < 256) { w0 = a.W_ih1[(size_t)row * 512 + 2 * kp];
                        w1 = a.W_ih1[(size_t)row * 512 + 2 * kp + 1]; }
        else          { w0 = a.W_hh1[(size_t)row * 512 + 2 * (kp - 256)];
                        w1 = a.W_hh1[(size_t)row * 512 + 2 * (kp - 256) + 1]; }
      }
      WLh[layer][kp][g] = packh2w(w0, w1);
    }
  }
  if (isAttn) sWV[tid] = a.wv[tid];
  const int vl = isAttn ? a.vlen[battn] : 0;
  const int hoff = isGru ? ((blk >> 1) * 128 + (blk & 1)) : 0;
  __syncthreads();

  for (int t = 0; t < TT; ++t) {
    const unsigned* h0p = (t == 0) ? a.h0i : a.h0S + (size_t)(t - 1) * STU;
    const unsigned* h1p = (t == 0) ? a.h1i : a.h1S + (size_t)(t - 1) * STU;
    unsigned* ctxu = a.ctxS + (size_t)t * STU;
    unsigned* h0n  = a.h0S + (size_t)t * STU;
    unsigned* h1n  = a.h1S + (size_t)t * STU;

    // ---- P1: attention (self-q) on attn blocks || Wh hoist on GRU blocks ----
    if (HOIST && isGru) {
      float s[6] = {0, 0, 0, 0, 0, 0};
      const int layer = (w >= 4) ? 1 : 0;
      const unsigned* xp = layer ? h1p : h0p;
      const int c = (w & 3) * 64;
      accum6(xp, c, WLh[layer], 256 + c, 64, lane, s);
#pragma unroll
      for (int g = 0; g < 6; ++g) redW[g][w][lane] = s[g];
      __syncthreads();
      if (tid < 128) {
        int b = tid & 63, jj = tid >> 6;
#pragma unroll
        for (int g = 0; g < 3; ++g) {
          int sl = 2 * g + jj;
          redH0s[sl][b] = redW[sl][0][b] + redW[sl][1][b] + redW[sl][2][b] + redW[sl][3][b];
          redH1s[sl][b] = redW[sl][4][b] + redW[sl][5][b] + redW[sl][6][b] + redW[sl][7][b];
        }
      }
    } else if (isAttn) {
      const int b = battn;
      if (tid < 256) sH2[tid] = h1p[(tid >> 1) * 128 + 2 * b + (tid & 1)];
      __syncthreads();
      {
        // q[j] = h1[b,:] . Wq[j,:], thread j, coalesced WqhT[kp][j] loads
        float q = 0.f;
        const unsigned* wq = a.WqhT + tid;
#pragma unroll 16
        for (int kp = 0; kp < 256; ++kp)
          q = __builtin_amdgcn_fdot2(bch(wq[(size_t)kp * HH]), bch(sH2[kp]), q, false);
        sQ[tid] = q;
      }
      __syncthreads();
      for (int s = w; s < SS; s += 8) {
        const unsigned* kp = a.keysph + ((size_t)b * SS + s) * 256;
        float p = 0.f;
#pragma unroll
        for (int i = 0; i < 4; ++i) {
          int hp = lane + 64 * i;           // h-pair index 0..255
          float2 kv = unpackh2(kp[hp]);
          p += tanh_fast(sQ[2 * hp] + kv.x) * sWV[2 * hp]
             + tanh_fast(sQ[2 * hp + 1] + kv.y) * sWV[2 * hp + 1];
        }
#pragma unroll
        for (int off = 32; off > 0; off >>= 1) p += __shfl_down(p, off);
        if (lane == 0) sAttn[s] = (s < vl) ? p : -1e6f;
      }
      __syncthreads();
      if (w == 0) {
        float v = sAttn[lane];
        float mx = v;
        for (int off = 32; off > 0; off >>= 1) mx = fmaxf(mx, __shfl_xor(mx, off));
        float e = __expf(v - mx);
        float sm = e;
        for (int off = 32; off > 0; off >>= 1) sm += __shfl_xor(sm, off);
        sAttn[lane] = e / sm;
      }
      __syncthreads();
      if (tid < 256) {
        float c0 = 0.f, c1 = 0.f;
        const unsigned* ep = a.ench + (size_t)b * SS * 256 + tid;
#pragma unroll 8
        for (int s = 0; s < SS; ++s) {
          float at = sAttn[s];
          float2 ev = unpackh2(ep[s * 256]);
          c0 += at * ev.x; c1 += at * ev.y;
        }
        sCt[2 * tid] = c0; sCt[2 * tid + 1] = c1;
      }
      __syncthreads();
      if (tid < 128) {
        uint2 v;
        v.x = packh2(sCt[4 * tid], sCt[4 * tid + 1]);
        v.y = packh2(sCt[4 * tid + 2], sCt[4 * tid + 3]);
        stg_scu2(&ctxu[tid * 128 + 2 * b], v);
      }
    }
    gbar<NBK>(a.flags, a.go, t * 3 + 1);

    // ---- P2: GRU layer 0 -> h0n ----
    if (isGru) {
      float gr0, gz0, gn0, gr1, gz1, gn1;
      unsigned holdu = 0;
      if (tid < 64) {
        const int b = tid;
        const float* gx = a.gixT + (size_t)t * G3 * BB;
        gr0 = gx[(size_t)(j0)*BB + b];          gr1 = gx[(size_t)(j0 + 1) * BB + b];
        gz0 = gx[(size_t)(j0 + 512) * BB + b];  gz1 = gx[(size_t)(j0 + 513) * BB + b];
        gn0 = gx[(size_t)(j0 + 1024) * BB + b]; gn1 = gx[(size_t)(j0 + 1025) * BB + b];
        holdu = h0p[hoff + 2 * b];
      }
      float s[6] = {0, 0, 0, 0, 0, 0};
      if (HOIST) {
        accum6(ctxu, w * 32, WLh[0], w * 32, 32, lane, s);
      } else {
        const int c = (w & 3) * 64;
        if (w < 4) accum6(ctxu, c, WLh[0], c, 64, lane, s);
        else       accum6(h0p,  c, WLh[0], 256 + c, 64, lane, s);
      }
#pragma unroll
      for (int g = 0; g < 6; ++g) redW[g][w][lane] = s[g];
      __syncthreads();
      if (tid < 64) {
        const int b = tid;
        float2 hold = unpackh2(holdu);
        float hv[2];
#pragma unroll
        for (int jj = 0; jj < 2; ++jj) {
          int j = j0 + jj;
          float Ri = 0, Zi = 0, Ni = 0, Rh = 0, Zh = 0, Nh = 0;
          if (HOIST) {
#pragma unroll
            for (int q = 0; q < 8; ++q) {
              Ri += redW[jj][q][b]; Zi += redW[2 + jj][q][b]; Ni += redW[4 + jj][q][b];
            }
            Rh = redH0s[jj][b]; Zh = redH0s[2 + jj][b]; Nh = redH0s[4 + jj][b];
          } else {
#pragma unroll
            for (int q = 0; q < 4; ++q) {
              Ri += redW[jj][q][b];     Rh += redW[jj][4 + q][b];
              Zi += redW[2 + jj][q][b]; Zh += redW[2 + jj][4 + q][b];
              Ni += redW[4 + jj][q][b]; Nh += redW[4 + jj][4 + q][b];
            }
          }
          float gr = jj ? gr1 : gr0, gz = jj ? gz1 : gz0, gn = jj ? gn1 : gn0;
          float r = sigmoid_fast(gr + Ri + a.b_hh0[j] + Rh);
          float z = sigmoid_fast(gz + Zi + a.b_hh0[j + 512] + Zh);
          float n = tanh_fast(gn + Ni + r * (a.b_hh0[j + 1024] + Nh));
          float ho = jj ? hold.y : hold.x;
          hv[jj] = (1.f - z) * n + z * ho;
        }
        stg_scu(&h0n[hoff + 2 * b], packh2(hv[0], hv[1]));
      }
    }
    gbar<NBK>(a.flags, a.go, t * 3 + 2);

    // ---- P3: GRU layer 1 -> h1n (+ bf16 outs) ----
    if (isGru) {
      unsigned holdu = 0;
      if (tid < 64) holdu = h1p[hoff + 2 * tid];
      float s[6] = {0, 0, 0, 0, 0, 0};
      if (HOIST) {
        accum6(h0n, w * 32, WLh[1], w * 32, 32, lane, s);
      } else {
        const int c = (w & 3) * 64;
        if (w < 4) accum6(h0n, c, WLh[1], c, 64, lane, s);
        else       accum6(h1p, c, WLh[1], 256 + c, 64, lane, s);
      }
#pragma unroll
      for (int g = 0; g < 6; ++g) redW[g][w][lane] = s[g];
      __syncthreads();
      if (tid < 64) {
        const int b = tid;
        float2 hold = unpackh2(holdu);
        float hv[2];
#pragma unroll
        for (int jj = 0; jj < 2; ++jj) {
          int j = j0 + jj;
          float Ri = 0, Zi = 0, Ni = 0, Rh = 0, Zh = 0, Nh = 0;
          if (HOIST) {
#pragma unroll
            for (int q = 0; q < 8; ++q) {
              Ri += redW[jj][q][b]; Zi += redW[2 + jj][q][b]; Ni += redW[4 + jj][q][b];
            }
            Rh = redH1s[jj][b]; Zh = redH1s[2 + jj][b]; Nh = redH1s[4 + jj][b];
          } else {
#pragma unroll
            for (int q = 0; q < 4; ++q) {
              Ri += redW[jj][q][b];     Rh += redW[jj][4 + q][b];
              Zi += redW[2 + jj][q][b]; Zh += redW[2 + jj][4 + q][b];
              Ni += redW[4 + jj][q][b]; Nh += redW[4 + jj][4 + q][b];
            }
          }
          float r = sigmoid_fast(a.b_ih1[j] + Ri + a.b_hh1[j] + Rh);
          float z = sigmoid_fast(a.b_ih1[j + 512] + Zi + a.b_hh1[j + 512] + Zh);
          float n = tanh_fast(a.b_ih1[j + 1024] + Ni + r * (a.b_hh1[j + 1024] + Nh));
          float ho = jj ? hold.y : hold.x;
          hv[jj] = (1.f - z) * n + z * ho;
          a.outsb[((size_t)t * BB + b) * HH + j] = __float2bfloat16(hv[jj]);
        }
        stg_scu(&h1n[hoff + 2 * b], packh2(hv[0], hv[1]));
      }
    }
    gbar<NBK>(a.flags, a.go, t * 3 + 3);
  }
}

// ---------------- final dense: C[m,v] = A[m,:] . Bt[v,:] + bias[v], scatter to [B,T,V]
__global__ __launch_bounds__(256) void dense_kernel(const __hip_bfloat16* __restrict__ A,
                                                    const __hip_bfloat16* __restrict__ Bt,
                                                    const float* __restrict__ bias,
                                                    float* __restrict__ out) {
  __shared__ __align__(16) short As[128 * 64];
  __shared__ __align__(16) short Bs[128 * 64];
  int mt = blockIdx.x;         // 0..31
  int nt = blockIdx.y;         // 0..249
  int tid = threadIdx.x;
  int w = tid >> 6, lane = tid & 63;
  int wm = w >> 1, wn = w & 1;
  f32x4 acc[4][4];
#pragma unroll
  for (int m = 0; m < 4; ++m)
#pragma unroll
    for (int n = 0; n < 4; ++n) acc[m][n] = (f32x4)0.f;

  const short* Ag = (const short*)A + (size_t)(mt * 128) * 512;
  const short* Bg = (const short*)Bt + (size_t)(nt * 128) * 512;

  for (int kt = 0; kt < 8; ++kt) {
    int k0 = kt * 64;
#pragma unroll
    for (int c = 0; c < 4; ++c) {
      int chunk = w * 4 + c;                  // 0..15, wave-uniform
      int row = chunk * 8 + (lane >> 3);      // 0..127
      int col = (lane & 7) * 8;               // bf16 col within 64
      async16(As + chunk * 512, Ag + (size_t)row * 512 + k0 + col);
      async16(Bs + chunk * 512, Bg + (size_t)row * 512 + k0 + col);
    }
    __syncthreads();
#pragma unroll
    for (int kk = 0; kk < 2; ++kk) {
      int krow = kk * 32 + (lane >> 4) * 8;
      bf16x8 af[4], bf[4];
#pragma unroll
      for (int m = 0; m < 4; ++m) {
        int r = wm * 64 + m * 16 + (lane & 15);
        af[m] = *(const bf16x8*)&As[r * 64 + krow];
      }
#pragma unroll
      for (int n = 0; n < 4; ++n) {
        int r = wn * 64 + n * 16 + (lane & 15);
        bf[n] = *(const bf16x8*)&Bs[r * 64 + krow];
      }
#pragma unroll
      for (int m = 0; m < 4; ++m)
#pragma unroll
        for (int n = 0; n < 4; ++n)
          acc[m][n] = __builtin_amdgcn_mfma_f32_16x16x32_bf16(af[m], bf[n], acc[m][n], 0, 0, 0);
    }
    __syncthreads();
  }
#pragma unroll
  for (int m = 0; m < 4; ++m) {
    int rbase = mt * 128 + wm * 64 + m * 16 + (lane >> 4) * 4;
#pragma unroll
    for (int n = 0; n < 4; ++n) {
      int v = nt * 128 + wn * 64 + n * 16 + (lane & 15);
      float bv = bias[v];
#pragma unroll
      for (int r = 0; r < 4; ++r) {
        int mi = rbase + r;                  // mi = t*64 + b
        size_t off = (size_t)(mi & 63) * (TT * VV) + (size_t)(mi >> 6) * VV + v;
        out[off] = acc[m][n][r] + bv;
      }
    }
  }
}

extern "C" void kernel_launch(void* const* d_in, const int* in_sizes, int n_in,
                              void* d_out, int out_size, void* d_ws, size_t ws_size,
                              hipStream_t stream) {
  const int*   X     = (const int*)d_in[0];
  const float* enc   = (const float*)d_in[1];
  const float* hs    = (const float*)d_in[2];
  const int*   vlen  = (const int*)d_in[3];
  const float* emb   = (const float*)d_in[4];
  const float* Wq    = (const float*)d_in[5];
  const float* Wk    = (const float*)d_in[6];
  const float* wv    = (const float*)d_in[7];
  const float* W_ih0 = (const float*)d_in[8];
  const float* W_hh0 = (const float*)d_in[9];
  const float* b_ih0 = (const float*)d_in[10];
  const float* b_hh0 = (const float*)d_in[11];
  const float* W_ih1 = (const float*)d_in[12];
  const float* W_hh1 = (const float*)d_in[13];
  const float* b_ih1 = (const float*)d_in[14];
  const float* b_hh1 = (const float*)d_in[15];
  const float* dW    = (const float*)d_in[16];
  const float* db    = (const float*)d_in[17];
  float* out = (float*)d_out;

  char* wp = (char*)d_ws;
  auto alloc = [&](size_t bytes) { char* p = wp; wp += (bytes + 255) & ~(size_t)255; return p; };
  __hip_bfloat16* dWb   = (__hip_bfloat16*)alloc((size_t)VV * HH * 2);
  __hip_bfloat16* outsb = (__hip_bfloat16*)alloc((size_t)TT * BB * HH * 2);
  float* keysp = (float*)alloc((size_t)BB * SS * HH * 4);
  float* gixT  = (float*)alloc((size_t)TT * G3 * BB * 4);
  float* WkT   = (float*)alloc((size_t)HH * HH * 4);
  float* WT0e  = (float*)alloc((size_t)EE * G3 * 4);
  unsigned* WqhT   = (unsigned*)alloc((size_t)256 * HH * 4);
  unsigned* keysph = (unsigned*)alloc((size_t)BB * SS * 256 * 4);
  unsigned* ench   = (unsigned*)alloc((size_t)BB * SS * 256 * 4);
  unsigned* h0i  = (unsigned*)alloc((size_t)STU * 4);
  unsigned* h1i  = (unsigned*)alloc((size_t)STU * 4);
  unsigned* ctxS = (unsigned*)alloc((size_t)TT * STU * 4);
  unsigned* h0S  = (unsigned*)alloc((size_t)TT * STU * 4);
  unsigned* h1S  = (unsigned*)alloc((size_t)TT * STU * 4);
  int* flags = (int*)alloc(320 * sizeof(int));
  int* go    = (int*)alloc(64 * sizeof(int));

  hipMemsetAsync(flags, 0, 320 * sizeof(int), stream);
  hipMemsetAsync(go, 0, 64 * sizeof(int), stream);

  dim3 tb(32, 8);
  transpose_kernel<<<dim3(HH / 32, HH / 32), tb, 0, stream>>>(WkT, Wk, HH, HH, HH, 0);
  transpose_kernel<<<dim3(EE / 32, G3 / 32), tb, 0, stream>>>(WT0e, W_ih0, G3, EE, HH + EE, HH);
  cast_kernel<<<2048, 256, 0, stream>>>(dW, dWb, VV * HH);
  hspack_kernel<<<128, 256, 0, stream>>>(hs, h0i, h1i);
  packWqT_kernel<<<dim3(256 / 32, HH / 32), tb, 0, stream>>>(Wq, WqhT);

  gemm32_kernel<<<dim3(BB * SS / 64, HH / 128), 256, 0, stream>>>(
      enc, nullptr, WkT, nullptr, keysp, HH, HH, HH, 0);
  gemm32_kernel<<<dim3(TT * BB / 64, G3 / 128), 256, 0, stream>>>(
      emb, X, WT0e, b_ih0, gixT, G3, EE, G3, 1);
  packhalf_kernel<<<1024, 256, 0, stream>>>(keysp, keysph, BB * SS * 256);
  packhalf_kernel<<<1024, 256, 0, stream>>>(enc, ench, BB * SS * 256);

  RecArgs args;
  args.W_ih0 = W_ih0; args.W_hh0 = W_hh0; args.W_ih1 = W_ih1; args.W_hh1 = W_hh1;
  args.b_hh0 = b_hh0; args.b_ih1 = b_ih1; args.b_hh1 = b_hh1;
  args.gixT = gixT; args.wv = wv; args.WqhT = WqhT;
  args.keysph = keysph; args.ench = ench; args.vlen = vlen;
  args.h0i = h0i; args.h1i = h1i;
  args.ctxS = ctxS; args.h0S = h0S; args.h1S = h1S;
  args.flags = flags; args.go = go; args.outsb = outsb;
  void* kp[] = {&args};

  // pick variant by queried co-residency capacity (deterministic per device)
  int maxb = 0;
  hipError_t qe = hipOccupancyMaxActiveBlocksPerMultiprocessor(
      &maxb, reinterpret_cast<const void*>(recurrent_kernel<true, 320>), 512, 0);
  bool launchedA = false;
  if (qe == hipSuccess && maxb >= 2) {
    hipError_t le = hipLaunchCooperativeKernel(
        reinterpret_cast<void*>(recurrent_kernel<true, 320>),
        dim3(320), dim3(512), kp, 0, stream);
    launchedA = (le == hipSuccess);
  }
  if (!launchedA) {
    hipLaunchCooperativeKernel(
        reinterpret_cast<void*>(recurrent_kernel<false, 256>),
        dim3(256), dim3(512), kp, 0, stream);
  }

  dense_kernel<<<dim3(32, 250), 256, 0, stream>>>(outsb, dWb, db, out);
}

// Round 17
// 1982.011 us; speedup vs baseline: 1.1414x; 1.1414x over previous
//
#include <hip/hip_runtime.h>
#include <hip/hip_bf16.h>
#include <hip/hip_fp16.h>

#define VV 32000
#define EE 256
#define HH 512
#define BB 64
#define TT 64
#define SS 64
#define G3 1536   // 3*H
#define NGRU 256
#define STU 16384 // one packed state buffer: 256 kp x 64 b uints, layout (kp>>1)*128 + 2b + (kp&1)

typedef __attribute__((ext_vector_type(8))) short bf16x8;
typedef __attribute__((ext_vector_type(4))) float f32x4;
typedef _Float16 half2v __attribute__((ext_vector_type(2)));

__device__ __forceinline__ half2v bch(unsigned u) { return __builtin_bit_cast(half2v, u); }

__device__ __forceinline__ void async16(void* lds, const void* g) {
  __builtin_amdgcn_global_load_lds((const __attribute__((address_space(1))) void*)g,
                                   (__attribute__((address_space(3))) void*)lds, 16, 0, 0);
}

__device__ __forceinline__ float sigmoid_fast(float x) {
  return 1.0f / (1.0f + __expf(-x));
}
__device__ __forceinline__ float tanh_fast(float x) {
  x = fminf(fmaxf(x, -15.f), 15.f);
  float e = __expf(2.f * x);
  return (e - 1.f) / (e + 1.f);
}
__device__ __forceinline__ float2 unpackh2(unsigned u) {
  __half2 h = *reinterpret_cast<__half2*>(&u);
  return __half22float2(h);
}
__device__ __forceinline__ unsigned packh2(float x, float y) {
  __half2 h = __floats2half2_rn(x, y);
  return *reinterpret_cast<unsigned*>(&h);
}
__device__ __forceinline__ unsigned packh2w(float x, float y) {  // weight pack
  half2v h; h[0] = (_Float16)x; h[1] = (_Float16)y;
  return __builtin_bit_cast(unsigned, h);
}

// coherent stores: write-through past L2 to the IF coherence point (no fence needed)
__device__ __forceinline__ void stg_sc(float* p, float v) {
  asm volatile("global_store_dword %0, %1, off sc0 sc1" :: "v"(p), "v"(v) : "memory");
}
__device__ __forceinline__ void stg_scu(unsigned* p, unsigned v) {
  asm volatile("global_store_dword %0, %1, off sc0 sc1" :: "v"(p), "v"(v) : "memory");
}
__device__ __forceinline__ void stg_scu2(unsigned* p, uint2 v) {
  asm volatile("global_store_dwordx2 %0, %1, off sc0 sc1" :: "v"(p), "v"(v) : "memory");
}
__device__ __forceinline__ void stg_sci(int* p, int v) {
  asm volatile("global_store_dword %0, %1, off sc0 sc1" :: "v"(p), "v"(v) : "memory");
}
__device__ __forceinline__ int ld_agent(const int* p) {
  return __hip_atomic_load(p, __ATOMIC_RELAXED, __HIP_MEMORY_SCOPE_AGENT);
}

// fence-free grid barrier, flag/master/broadcast form (r13-proven: ~3.5us).
template <int NBK>
__device__ __forceinline__ void gbar(int* flags, int* go, int phase) {
  __syncthreads();   // drains vmcnt per wave -> this block's sc stores are at IF
  if (blockIdx.x == NBK - 1) {
    if (threadIdx.x < 64) {
      const int l = threadIdx.x;
      if (l == 0) stg_sci(&flags[NBK - 1], phase);
      for (;;) {
        bool ok = true;
#pragma unroll
        for (int g = 0; g < NBK / 64; ++g) ok &= (ld_agent(&flags[l + 64 * g]) >= phase);
        if (__all(ok)) break;
        __builtin_amdgcn_s_sleep(1);
      }
      if (l == 0) stg_sci(go, phase);
    }
  } else {
    if (threadIdx.x == 0) {
      stg_sci(&flags[blockIdx.x], phase);
      while (ld_agent(go) < phase) __builtin_amdgcn_s_sleep(1);
    }
  }
  __syncthreads();
}

// ---------------- fp32 -> bf16 cast
__global__ __launch_bounds__(256) void cast_kernel(const float* __restrict__ src,
                                                   __hip_bfloat16* __restrict__ dst, int n) {
  for (int i = blockIdx.x * blockDim.x + threadIdx.x; i < n; i += gridDim.x * blockDim.x)
    dst[i] = __float2bfloat16(src[i]);
}

// ---------------- strided fp32 -> bf16 cast: dst[r][c] = src[r*ld + off + c]
__global__ __launch_bounds__(256) void cast_strided_kernel(const float* __restrict__ src,
                                                           __hip_bfloat16* __restrict__ dst,
                                                           int rows, int cols, int ld, int off) {
  int n = rows * cols;
  for (int i = blockIdx.x * blockDim.x + threadIdx.x; i < n; i += gridDim.x * blockDim.x) {
    int r = i / cols, c = i - r * cols;
    dst[i] = __float2bfloat16(src[(size_t)r * ld + off + c]);
  }
}

// ---------------- fp32 pairs -> packed fp16 (half2) words
__global__ __launch_bounds__(256) void packhalf_kernel(const float* __restrict__ src,
                                                       unsigned* __restrict__ dst, int npairs) {
  for (int i = blockIdx.x * blockDim.x + threadIdx.x; i < npairs; i += gridDim.x * blockDim.x)
    dst[i] = packh2(src[2 * i], src[2 * i + 1]);
}

// ---------------- pack initial hidden state into (kp>>1)*128+2b+(kp&1) fp16-pair layout
__global__ __launch_bounds__(256) void hspack_kernel(const float* __restrict__ hs,
                                                     unsigned* __restrict__ h0u,
                                                     unsigned* __restrict__ h1u) {
  int i = blockIdx.x * 256 + threadIdx.x;   // 0..32767
  int layer = i >> 14, r = i & 16383;
  int b = r >> 8, kp = r & 255;
  const float* src = hs + (size_t)layer * BB * HH + (size_t)b * HH + 2 * kp;
  unsigned u = packh2(src[0], src[1]);
  (layer ? h1u : h0u)[(kp >> 1) * 128 + 2 * b + (kp & 1)] = u;
}

// ---------------- generic MFMA bf16 GEMM: C[m][v] = A[row(m)][:].Bt[v][:] (+bias[v])
// M fixed 4096 (grid.x=32), tile 128x128, K = KTILES*64.
// row(m) = Xtb ? Xtb[(m&63)*TT + (m>>6)] : m.
// tbmaj==0: C[m][v] (ld N);  tbmaj==1: C[(m>>6)][v][m&63]  ([t][n][b]).
template <int KTILES>
__global__ __launch_bounds__(256) void mfma_gemm_kernel(
    const __hip_bfloat16* __restrict__ A, const int* __restrict__ Xtb,
    const __hip_bfloat16* __restrict__ Bt, int ldbt,
    const float* __restrict__ bias, float* __restrict__ C, int N, int tbmaj) {
  constexpr int K = KTILES * 64;
  __shared__ __align__(16) short As[128 * 64];
  __shared__ __align__(16) short Bs[128 * 64];
  __shared__ int toks[128];
  int mt = blockIdx.x, nt = blockIdx.y;
  int tid = threadIdx.x;
  int w = tid >> 6, lane = tid & 63;
  int wm = w >> 1, wn = w & 1;
  if (tid < 128) {
    int row = mt * 128 + tid;
    toks[tid] = Xtb ? Xtb[(row & 63) * TT + (row >> 6)] : row;
  }
  __syncthreads();
  f32x4 acc[4][4];
#pragma unroll
  for (int m = 0; m < 4; ++m)
#pragma unroll
    for (int n = 0; n < 4; ++n) acc[m][n] = (f32x4)0.f;

  const short* Bg = (const short*)Bt + (size_t)(nt * 128) * ldbt;
  for (int kt = 0; kt < KTILES; ++kt) {
    int k0 = kt * 64;
#pragma unroll
    for (int c = 0; c < 4; ++c) {
      int chunk = w * 4 + c;                  // 0..15
      int row = chunk * 8 + (lane >> 3);      // 0..127
      int col = (lane & 7) * 8;
      async16(As + chunk * 512, (const short*)A + (size_t)toks[row] * K + k0 + col);
      async16(Bs + chunk * 512, Bg + (size_t)row * ldbt + k0 + col);
    }
    __syncthreads();
#pragma unroll
    for (int kk = 0; kk < 2; ++kk) {
      int krow = kk * 32 + (lane >> 4) * 8;
      bf16x8 af[4], bf[4];
#pragma unroll
      for (int m = 0; m < 4; ++m) {
        int r = wm * 64 + m * 16 + (lane & 15);
        af[m] = *(const bf16x8*)&As[r * 64 + krow];
      }
#pragma unroll
      for (int n = 0; n < 4; ++n) {
        int r = wn * 64 + n * 16 + (lane & 15);
        bf[n] = *(const bf16x8*)&Bs[r * 64 + krow];
      }
#pragma unroll
      for (int m = 0; m < 4; ++m)
#pragma unroll
        for (int n = 0; n < 4; ++n)
          acc[m][n] = __builtin_amdgcn_mfma_f32_16x16x32_bf16(af[m], bf[n], acc[m][n], 0, 0, 0);
    }
    __syncthreads();
  }
#pragma unroll
  for (int m = 0; m < 4; ++m) {
    int rbase = mt * 128 + wm * 64 + m * 16 + (lane >> 4) * 4;
#pragma unroll
    for (int n = 0; n < 4; ++n) {
      int v = nt * 128 + wn * 64 + n * 16 + (lane & 15);
      float bv = bias ? bias[v] : 0.f;
#pragma unroll
      for (int r = 0; r < 4; ++r) {
        int mi = rbase + r;
        float val = acc[m][n][r] + bv;
        if (tbmaj) C[((size_t)(mi >> 6) * N + v) * BB + (mi & 63)] = val;
        else       C[(size_t)mi * N + v] = val;
      }
    }
  }
}

// ---------------- persistent recurrent kernel (r15-exact: 4 phases) ----------------
struct RecArgs {
  const float *Wq, *W_ih0, *W_hh0, *W_ih1, *W_hh1;
  const float *b_hh0, *b_ih1, *b_hh1;
  const float *gixT, *wv;           // gixT: [t][j(1536)][b] fp32
  const unsigned *keysph, *ench;    // fp16-packed [b*S+s][h/2]
  const int* vlen;
  const unsigned *h0i, *h1i;        // packed init state
  float *qS;                        // [TT][b][j] fp32 one-shot
  unsigned *ctxS, *h0S, *h1S;       // [TT][STU] one-shot
  int *flags, *go;
  __hip_bfloat16* outsb;
};

// fdot2 accumulation over nkp k-pairs (x packed fp16 state, W fp16 LDS).
__device__ __forceinline__ void accum6(const unsigned* __restrict__ xu, int xkp0,
                                       const unsigned (*__restrict__ WL)[8], int wkp0,
                                       int nkp, int b, float s[6]) {
#pragma unroll 4
  for (int i = 0; i < nkp; i += 2) {
    uint2 xv = *(const uint2*)(xu + ((xkp0 + i) >> 1) * 128 + 2 * b);
    half2v x0 = bch(xv.x), x1 = bch(xv.y);
    const unsigned* w0 = WL[wkp0 + i];
    const unsigned* w1 = WL[wkp0 + i + 1];
#pragma unroll
    for (int g = 0; g < 6; ++g) {
      s[g] = __builtin_amdgcn_fdot2(bch(w0[g]), x0, s[g], false);
      s[g] = __builtin_amdgcn_fdot2(bch(w1[g]), x1, s[g], false);
    }
  }
}

template <bool HOIST, int NBK>
__global__ __launch_bounds__(512, 4) void recurrent_kernel(RecArgs a) {
  const int blk = blockIdx.x, tid = threadIdx.x;
  const int w = tid >> 6, lane = tid & 63;
  const bool isGru = HOIST ? (blk < NGRU) : true;
  const bool isAttn = HOIST ? (blk >= NGRU) : (blk < BB);
  const int battn = HOIST ? (blk - NGRU) : blk;
  const int j0 = 2 * blk;   // valid for GRU blocks

  __shared__ __align__(16) unsigned WLh[2][512][8];  // [layer][kp][slot r0,r1,z0,z1,n0,n1,pad,pad]
  __shared__ __align__(16) unsigned QLh[256][2];     // q weights, kp x {j0,j0+1}
  __shared__ float redW[6][8][64];
  __shared__ float redH0s[6][64], redH1s[6][64];
  __shared__ float sQ[HH], sWV[HH], sCt[HH], sAttn[SS];

  // one-time fp16 weight preload
  if (isGru) {
    for (int idx = tid; idx < 2 * 3072; idx += 512) {
      int layer = idx / 3072;
      int rem = idx - layer * 3072;
      int kp = rem / 6, g = rem - kp * 6;
      int gate = g >> 1, jj = g & 1;
      int row = gate * 512 + j0 + jj;
      float w0, w1;
      if (layer == 0) {
        if (kp < 256) { w0 = a.W_ih0[(size_t)row * 768 + 2 * kp];
                        w1 = a.W_ih0[(size_t)row * 768 + 2 * kp + 1]; }
        else          { w0 = a.W_hh0[(size_t)row * 512 + 2 * (kp - 256)];
                        w1 = a.W_hh0[(size_t)row * 512 + 2 * (kp - 256) + 1]; }
      } else {
        if (kp < 256) { w0 = a.W_ih1[(size_t)row * 512 + 2 * kp];
                        w1 = a.W_ih1[(size_t)row * 512 + 2 * kp + 1]; }
        else          { w0 = a.W_hh1[(size_t)row * 512 + 2 * (kp - 256)];
                        w1 = a.W_hh1[(size_t)row * 512 + 2 * (kp - 256) + 1]; }
      }
      WLh[layer][kp][g] = packh2w(w0, w1);
    }
    {
      int kp = tid >> 1, jj = tid & 1;   // 512 threads cover 256x2
      QLh[kp][jj] = packh2w(a.Wq[(size_t)(j0 + jj) * HH + 2 * kp],
                            a.Wq[(size_t)(j0 + jj) * HH + 2 * kp + 1]);
    }
  }
  if (isAttn) sWV[tid] = a.wv[tid];
  const int vl = isAttn ? a.vlen[battn] : 0;
  const int hoff = isGru ? ((blk >> 1) * 128 + (blk & 1)) : 0;
  __syncthreads();

  for (int t = 0; t < TT; ++t) {
    const unsigned* h0p = (t == 0) ? a.h0i : a.h0S + (size_t)(t - 1) * STU;
    const unsigned* h1p = (t == 0) ? a.h1i : a.h1S + (size_t)(t - 1) * STU;
    float* qrowT = a.qS + (size_t)t * BB * HH;   // [b][j] fp32
    unsigned* ctxu = a.ctxS + (size_t)t * STU;
    unsigned* h0n  = a.h0S + (size_t)t * STU;
    unsigned* h1n  = a.h1S + (size_t)t * STU;

    // ---- P0: q[b][j0..j0+1] (GRU blocks, kp-split over 8 waves) ----
    if (isGru) {
      float q0 = 0.f, q1 = 0.f;
      const int kp0 = w * 32;
#pragma unroll 4
      for (int i = 0; i < 32; i += 2) {
        uint2 xv = *(const uint2*)(h1p + ((kp0 + i) >> 1) * 128 + 2 * lane);
        half2v x0 = bch(xv.x), x1 = bch(xv.y);
        q0 = __builtin_amdgcn_fdot2(bch(QLh[kp0 + i][0]), x0, q0, false);
        q0 = __builtin_amdgcn_fdot2(bch(QLh[kp0 + i + 1][0]), x1, q0, false);
        q1 = __builtin_amdgcn_fdot2(bch(QLh[kp0 + i][1]), x0, q1, false);
        q1 = __builtin_amdgcn_fdot2(bch(QLh[kp0 + i + 1][1]), x1, q1, false);
      }
      redW[0][w][lane] = q0; redW[1][w][lane] = q1;
      __syncthreads();
      if (tid < 64) {
        int b = tid;
        float v0 = 0.f, v1 = 0.f;
#pragma unroll
        for (int q = 0; q < 8; ++q) { v0 += redW[0][q][b]; v1 += redW[1][q][b]; }
        stg_sc(&qrowT[(size_t)b * HH + j0], v0);
        stg_sc(&qrowT[(size_t)b * HH + j0 + 1], v1);
      }
    }
    gbar<NBK>(a.flags, a.go, t * 4 + 1);

    // ---- P1: attention (attn blocks) || Wh hoist (GRU blocks, HOIST only) ----
    if (HOIST && isGru) {
      float s[6] = {0, 0, 0, 0, 0, 0};
      const int layer = (w >= 4) ? 1 : 0;
      const unsigned* xp = layer ? h1p : h0p;
      const int c = (w & 3) * 64;
      accum6(xp, c, WLh[layer], 256 + c, 64, lane, s);
#pragma unroll
      for (int g = 0; g < 6; ++g) redW[g][w][lane] = s[g];
      __syncthreads();
      if (tid < 128) {
        int b = tid & 63, jj = tid >> 6;
#pragma unroll
        for (int g = 0; g < 3; ++g) {
          int sl = 2 * g + jj;
          redH0s[sl][b] = redW[sl][0][b] + redW[sl][1][b] + redW[sl][2][b] + redW[sl][3][b];
          redH1s[sl][b] = redW[sl][4][b] + redW[sl][5][b] + redW[sl][6][b] + redW[sl][7][b];
        }
      }
    } else if (isAttn) {
      const int b = battn;
      sQ[tid] = qrowT[(size_t)b * HH + tid];
      __syncthreads();
      for (int s = w; s < SS; s += 8) {
        const unsigned* kp = a.keysph + ((size_t)b * SS + s) * 256;
        float p = 0.f;
#pragma unroll
        for (int i = 0; i < 4; ++i) {
          int hp = lane + 64 * i;           // h-pair index 0..255
          float2 kv = unpackh2(kp[hp]);
          p += tanh_fast(sQ[2 * hp] + kv.x) * sWV[2 * hp]
             + tanh_fast(sQ[2 * hp + 1] + kv.y) * sWV[2 * hp + 1];
        }
#pragma unroll
        for (int off = 32; off > 0; off >>= 1) p += __shfl_down(p, off);
        if (lane == 0) sAttn[s] = (s < vl) ? p : -1e6f;
      }
      __syncthreads();
      if (w == 0) {
        float v = sAttn[lane];
        float mx = v;
        for (int off = 32; off > 0; off >>= 1) mx = fmaxf(mx, __shfl_xor(mx, off));
        float e = __expf(v - mx);
        float sm = e;
        for (int off = 32; off > 0; off >>= 1) sm += __shfl_xor(sm, off);
        sAttn[lane] = e / sm;
      }
      __syncthreads();
      if (tid < 256) {
        float c0 = 0.f, c1 = 0.f;
        const unsigned* ep = a.ench + (size_t)b * SS * 256 + tid;
#pragma unroll 8
        for (int s = 0; s < SS; ++s) {
          float at = sAttn[s];
          float2 ev = unpackh2(ep[s * 256]);
          c0 += at * ev.x; c1 += at * ev.y;
        }
        sCt[2 * tid] = c0; sCt[2 * tid + 1] = c1;
      }
      __syncthreads();
      if (tid < 128) {
        uint2 v;
        v.x = packh2(sCt[4 * tid], sCt[4 * tid + 1]);
        v.y = packh2(sCt[4 * tid + 2], sCt[4 * tid + 3]);
        stg_scu2(&ctxu[tid * 128 + 2 * b], v);
      }
    }
    gbar<NBK>(a.flags, a.go, t * 4 + 2);

    // ---- P2: GRU layer 0 -> h0n ----
    if (isGru) {
      float gr0, gz0, gn0, gr1, gz1, gn1;
      unsigned holdu = 0;
      if (tid < 64) {
        const int b = tid;
        const float* gx = a.gixT + (size_t)t * G3 * BB;
        gr0 = gx[(size_t)(j0)*BB + b];          gr1 = gx[(size_t)(j0 + 1) * BB + b];
        gz0 = gx[(size_t)(j0 + 512) * BB + b];  gz1 = gx[(size_t)(j0 + 513) * BB + b];
        gn0 = gx[(size_t)(j0 + 1024) * BB + b]; gn1 = gx[(size_t)(j0 + 1025) * BB + b];
        holdu = h0p[hoff + 2 * b];
      }
      float s[6] = {0, 0, 0, 0, 0, 0};
      if (HOIST) {
        accum6(ctxu, w * 32, WLh[0], w * 32, 32, lane, s);
      } else {
        const int c = (w & 3) * 64;
        if (w < 4) accum6(ctxu, c, WLh[0], c, 64, lane, s);
        else       accum6(h0p,  c, WLh[0], 256 + c, 64, lane, s);
      }
#pragma unroll
      for (int g = 0; g < 6; ++g) redW[g][w][lane] = s[g];
      __syncthreads();
      if (tid < 64) {
        const int b = tid;
        float2 hold = unpackh2(holdu);
        float hv[2];
#pragma unroll
        for (int jj = 0; jj < 2; ++jj) {
          int j = j0 + jj;
          float Ri = 0, Zi = 0, Ni = 0, Rh = 0, Zh = 0, Nh = 0;
          if (HOIST) {
#pragma unroll
            for (int q = 0; q < 8; ++q) {
              Ri += redW[jj][q][b]; Zi += redW[2 + jj][q][b]; Ni += redW[4 + jj][q][b];
            }
            Rh = redH0s[jj][b]; Zh = redH0s[2 + jj][b]; Nh = redH0s[4 + jj][b];
          } else {
#pragma unroll
            for (int q = 0; q < 4; ++q) {
              Ri += redW[jj][q][b];     Rh += redW[jj][4 + q][b];
              Zi += redW[2 + jj][q][b]; Zh += redW[2 + jj][4 + q][b];
              Ni += redW[4 + jj][q][b]; Nh += redW[4 + jj][4 + q][b];
            }
          }
          float gr = jj ? gr1 : gr0, gz = jj ? gz1 : gz0, gn = jj ? gn1 : gn0;
          float r = sigmoid_fast(gr + Ri + a.b_hh0[j] + Rh);
          float z = sigmoid_fast(gz + Zi + a.b_hh0[j + 512] + Zh);
          float n = tanh_fast(gn + Ni + r * (a.b_hh0[j + 1024] + Nh));
          float ho = jj ? hold.y : hold.x;
          hv[jj] = (1.f - z) * n + z * ho;
        }
        stg_scu(&h0n[hoff + 2 * b], packh2(hv[0], hv[1]));
      }
    }
    gbar<NBK>(a.flags, a.go, t * 4 + 3);

    // ---- P3: GRU layer 1 -> h1n (+ bf16 outs) ----
    if (isGru) {
      unsigned holdu = 0;
      if (tid < 64) holdu = h1p[hoff + 2 * tid];
      float s[6] = {0, 0, 0, 0, 0, 0};
      if (HOIST) {
        accum6(h0n, w * 32, WLh[1], w * 32, 32, lane, s);
      } else {
        const int c = (w & 3) * 64;
        if (w < 4) accum6(h0n, c, WLh[1], c, 64, lane, s);
        else       accum6(h1p, c, WLh[1], 256 + c, 64, lane, s);
      }
#pragma unroll
      for (int g = 0; g < 6; ++g) redW[g][w][lane] = s[g];
      __syncthreads();
      if (tid < 64) {
        const int b = tid;
        float2 hold = unpackh2(holdu);
        float hv[2];
#pragma unroll
        for (int jj = 0; jj < 2; ++jj) {
          int j = j0 + jj;
          float Ri = 0, Zi = 0, Ni = 0, Rh = 0, Zh = 0, Nh = 0;
          if (HOIST) {
#pragma unroll
            for (int q = 0; q < 8; ++q) {
              Ri += redW[jj][q][b]; Zi += redW[2 + jj][q][b]; Ni += redW[4 + jj][q][b];
            }
            Rh = redH1s[jj][b]; Zh = redH1s[2 + jj][b]; Nh = redH1s[4 + jj][b];
          } else {
#pragma unroll
            for (int q = 0; q < 4; ++q) {
              Ri += redW[jj][q][b];     Rh += redW[jj][4 + q][b];
              Zi += redW[2 + jj][q][b]; Zh += redW[2 + jj][4 + q][b];
              Ni += redW[4 + jj][q][b]; Nh += redW[4 + jj][4 + q][b];
            }
          }
          float r = sigmoid_fast(a.b_ih1[j] + Ri + a.b_hh1[j] + Rh);
          float z = sigmoid_fast(a.b_ih1[j + 512] + Zi + a.b_hh1[j + 512] + Zh);
          float n = tanh_fast(a.b_ih1[j + 1024] + Ni + r * (a.b_hh1[j + 1024] + Nh));
          float ho = jj ? hold.y : hold.x;
          hv[jj] = (1.f - z) * n + z * ho;
          a.outsb[((size_t)t * BB + b) * HH + j] = __float2bfloat16(hv[jj]);
        }
        stg_scu(&h1n[hoff + 2 * b], packh2(hv[0], hv[1]));
      }
    }
    gbar<NBK>(a.flags, a.go, t * 4 + 4);
  }
}

// ---------------- final dense: C[m,v] = A[m,:] . Bt[v,:] + bias[v], scatter to [B,T,V]
__global__ __launch_bounds__(256) void dense_kernel(const __hip_bfloat16* __restrict__ A,
                                                    const __hip_bfloat16* __restrict__ Bt,
                                                    const float* __restrict__ bias,
                                                    float* __restrict__ out) {
  __shared__ __align__(16) short As[128 * 64];
  __shared__ __align__(16) short Bs[128 * 64];
  int mt = blockIdx.x;         // 0..31
  int nt = blockIdx.y;         // 0..249
  int tid = threadIdx.x;
  int w = tid >> 6, lane = tid & 63;
  int wm = w >> 1, wn = w & 1;
  f32x4 acc[4][4];
#pragma unroll
  for (int m = 0; m < 4; ++m)
#pragma unroll
    for (int n = 0; n < 4; ++n) acc[m][n] = (f32x4)0.f;

  const short* Ag = (const short*)A + (size_t)(mt * 128) * 512;
  const short* Bg = (const short*)Bt + (size_t)(nt * 128) * 512;

  for (int kt = 0; kt < 8; ++kt) {
    int k0 = kt * 64;
#pragma unroll
    for (int c = 0; c < 4; ++c) {
      int chunk = w * 4 + c;                  // 0..15, wave-uniform
      int row = chunk * 8 + (lane >> 3);      // 0..127
      int col = (lane & 7) * 8;               // bf16 col within 64
      async16(As + chunk * 512, Ag + (size_t)row * 512 + k0 + col);
      async16(Bs + chunk * 512, Bg + (size_t)row * 512 + k0 + col);
    }
    __syncthreads();
#pragma unroll
    for (int kk = 0; kk < 2; ++kk) {
      int krow = kk * 32 + (lane >> 4) * 8;
      bf16x8 af[4], bf[4];
#pragma unroll
      for (int m = 0; m < 4; ++m) {
        int r = wm * 64 + m * 16 + (lane & 15);
        af[m] = *(const bf16x8*)&As[r * 64 + krow];
      }
#pragma unroll
      for (int n = 0; n < 4; ++n) {
        int r = wn * 64 + n * 16 + (lane & 15);
        bf[n] = *(const bf16x8*)&Bs[r * 64 + krow];
      }
#pragma unroll
      for (int m = 0; m < 4; ++m)
#pragma unroll
        for (int n = 0; n < 4; ++n)
          acc[m][n] = __builtin_amdgcn_mfma_f32_16x16x32_bf16(af[m], bf[n], acc[m][n], 0, 0, 0);
    }
    __syncthreads();
  }
#pragma unroll
  for (int m = 0; m < 4; ++m) {
    int rbase = mt * 128 + wm * 64 + m * 16 + (lane >> 4) * 4;
#pragma unroll
    for (int n = 0; n < 4; ++n) {
      int v = nt * 128 + wn * 64 + n * 16 + (lane & 15);
      float bv = bias[v];
#pragma unroll
      for (int r = 0; r < 4; ++r) {
        int mi = rbase + r;                  // mi = t*64 + b
        size_t off = (size_t)(mi & 63) * (TT * VV) + (size_t)(mi >> 6) * VV + v;
        out[off] = acc[m][n][r] + bv;
      }
    }
  }
}

extern "C" void kernel_launch(void* const* d_in, const int* in_sizes, int n_in,
                              void* d_out, int out_size, void* d_ws, size_t ws_size,
                              hipStream_t stream) {
  const int*   X     = (const int*)d_in[0];
  const float* enc   = (const float*)d_in[1];
  const float* hs    = (const float*)d_in[2];
  const int*   vlen  = (const int*)d_in[3];
  const float* emb   = (const float*)d_in[4];
  const float* Wq    = (const float*)d_in[5];
  const float* Wk    = (const float*)d_in[6];
  const float* wv    = (const float*)d_in[7];
  const float* W_ih0 = (const float*)d_in[8];
  const float* W_hh0 = (const float*)d_in[9];
  const float* b_ih0 = (const float*)d_in[10];
  const float* b_hh0 = (const float*)d_in[11];
  const float* W_ih1 = (const float*)d_in[12];
  const float* W_hh1 = (const float*)d_in[13];
  const float* b_ih1 = (const float*)d_in[14];
  const float* b_hh1 = (const float*)d_in[15];
  const float* dW    = (const float*)d_in[16];
  const float* db    = (const float*)d_in[17];
  float* out = (float*)d_out;

  char* wp = (char*)d_ws;
  auto alloc = [&](size_t bytes) { char* p = wp; wp += (bytes + 255) & ~(size_t)255; return p; };
  __hip_bfloat16* dWb   = (__hip_bfloat16*)alloc((size_t)VV * HH * 2);
  __hip_bfloat16* outsb = (__hip_bfloat16*)alloc((size_t)TT * BB * HH * 2);
  __hip_bfloat16* encb  = (__hip_bfloat16*)alloc((size_t)BB * SS * HH * 2);
  __hip_bfloat16* embb  = (__hip_bfloat16*)alloc((size_t)VV * EE * 2);
  __hip_bfloat16* Wkb   = (__hip_bfloat16*)alloc((size_t)HH * HH * 2);
  __hip_bfloat16* Wieb  = (__hip_bfloat16*)alloc((size_t)G3 * EE * 2);
  float* keysp = (float*)alloc((size_t)BB * SS * HH * 4);
  float* gixT  = (float*)alloc((size_t)TT * G3 * BB * 4);
  float* qS    = (float*)alloc((size_t)TT * BB * HH * 4);
  unsigned* keysph = (unsigned*)alloc((size_t)BB * SS * 256 * 4);
  unsigned* ench   = (unsigned*)alloc((size_t)BB * SS * 256 * 4);
  unsigned* h0i  = (unsigned*)alloc((size_t)STU * 4);
  unsigned* h1i  = (unsigned*)alloc((size_t)STU * 4);
  unsigned* ctxS = (unsigned*)alloc((size_t)TT * STU * 4);
  unsigned* h0S  = (unsigned*)alloc((size_t)TT * STU * 4);
  unsigned* h1S  = (unsigned*)alloc((size_t)TT * STU * 4);
  int* flags = (int*)alloc(320 * sizeof(int));
  int* go    = (int*)alloc(64 * sizeof(int));

  hipMemsetAsync(flags, 0, 320 * sizeof(int), stream);
  hipMemsetAsync(go, 0, 64 * sizeof(int), stream);

  // prep: casts
  cast_kernel<<<2048, 256, 0, stream>>>(dW, dWb, VV * HH);
  cast_kernel<<<512, 256, 0, stream>>>(enc, encb, BB * SS * HH);
  cast_kernel<<<1024, 256, 0, stream>>>(emb, embb, VV * EE);
  cast_kernel<<<256, 256, 0, stream>>>(Wk, Wkb, HH * HH);
  cast_strided_kernel<<<256, 256, 0, stream>>>(W_ih0, Wieb, G3, EE, HH + EE, HH);
  hspack_kernel<<<128, 256, 0, stream>>>(hs, h0i, h1i);

  // keysp[b*S+s][n] = enc row . Wk[n,:]   (M=4096, N=512, K=512, Bt = Wk row-major)
  mfma_gemm_kernel<8><<<dim3(32, HH / 128), 256, 0, stream>>>(
      encb, nullptr, Wkb, HH, nullptr, keysp, HH, 0);
  // gixT[t][n][b] = emb[X[b,t]] . W_ih0[n, 512:768] + b_ih0  (M=4096, N=1536, K=256)
  mfma_gemm_kernel<4><<<dim3(32, G3 / 128), 256, 0, stream>>>(
      embb, X, Wieb, EE, b_ih0, gixT, G3, 1);

  packhalf_kernel<<<1024, 256, 0, stream>>>(keysp, keysph, BB * SS * 256);
  packhalf_kernel<<<1024, 256, 0, stream>>>(enc, ench, BB * SS * 256);

  RecArgs args;
  args.Wq = Wq; args.W_ih0 = W_ih0; args.W_hh0 = W_hh0; args.W_ih1 = W_ih1; args.W_hh1 = W_hh1;
  args.b_hh0 = b_hh0; args.b_ih1 = b_ih1; args.b_hh1 = b_hh1;
  args.gixT = gixT; args.wv = wv; args.keysph = keysph; args.ench = ench; args.vlen = vlen;
  args.h0i = h0i; args.h1i = h1i;
  args.qS = qS; args.ctxS = ctxS; args.h0S = h0S; args.h1S = h1S;
  args.flags = flags; args.go = go; args.outsb = outsb;
  void* kp[] = {&args};

  // pick variant by queried co-residency capacity (deterministic per device)
  int maxb = 0;
  hipError_t qe = hipOccupancyMaxActiveBlocksPerMultiprocessor(
      &maxb, reinterpret_cast<const void*>(recurrent_kernel<true, 320>), 512, 0);
  bool launchedA = false;
  if (qe == hipSuccess && maxb >= 2) {
    hipError_t le = hipLaunchCooperativeKernel(
        reinterpret_cast<void*>(recurrent_kernel<true, 320>),
        dim3(320), dim3(512), kp, 0, stream);
    launchedA = (le == hipSuccess);
  }
  if (!launchedA) {
    hipLaunchCooperativeKernel(
        reinterpret_cast<void*>(recurrent_kernel<false, 256>),
        dim3(256), dim3(512), kp, 0, stream);
  }

  dense_kernel<<<dim3(32, 250), 256, 0, stream>>>(outsb, dWb, db, out);
}